// Round 1
// baseline (649.114 us; speedup 1.0000x reference)
//
#include <hip/hip_runtime.h>

#define BN_EPS 1e-5f

// ---------------- CSR build ----------------

__global__ void count_kernel(const int* __restrict__ ei, int E, int* __restrict__ cnt) {
    int e = blockIdx.x * blockDim.x + threadIdx.x;
    if (e < E) atomicAdd(&cnt[ei[E + e]], 1);
}

__global__ void dinv_kernel(const int* __restrict__ cnt, float* __restrict__ dinv, int N) {
    int i = blockIdx.x * blockDim.x + threadIdx.x;
    if (i < N) dinv[i] = rsqrtf((float)(cnt[i] + 1));  // +1 self loop
}

__global__ __launch_bounds__(1024) void scan_blocks(const int* __restrict__ cnt,
                                                    int* __restrict__ rowptr,
                                                    int* __restrict__ bsum, int N) {
    __shared__ int sh[1024];
    int t = threadIdx.x;
    int i = blockIdx.x * 1024 + t;
    int v = (i < N) ? cnt[i] : 0;
    sh[t] = v;
    __syncthreads();
    for (int off = 1; off < 1024; off <<= 1) {
        int x = (t >= off) ? sh[t - off] : 0;
        __syncthreads();
        sh[t] += x;
        __syncthreads();
    }
    if (i < N) rowptr[i] = sh[t] - v;          // block-local exclusive prefix
    if (t == 1023) bsum[blockIdx.x] = sh[1023];
}

__global__ void scan_carry(const int* __restrict__ bsum, int* __restrict__ boff, int nblk) {
    if (threadIdx.x == 0 && blockIdx.x == 0) {
        int run = 0;
        for (int b = 0; b < nblk; ++b) { int v = bsum[b]; boff[b] = run; run += v; }
        boff[nblk] = run;
    }
}

__global__ void scan_add(int* __restrict__ rowptr, const int* __restrict__ boff,
                         int* __restrict__ cursor, int N, int nblk) {
    int i = blockIdx.x * blockDim.x + threadIdx.x;
    if (i < N) {
        int v = rowptr[i] + boff[i >> 10];
        rowptr[i] = v;
        cursor[i] = v;
    }
    if (i == 0) rowptr[N] = boff[nblk];
}

__global__ void fill_kernel(const int* __restrict__ ei, int E, int* __restrict__ cursor,
                            const float* __restrict__ dinv, int* __restrict__ eidx,
                            float* __restrict__ enorm) {
    int e = blockIdx.x * blockDim.x + threadIdx.x;
    if (e < E) {
        int s = ei[e], d = ei[E + e];
        int p = atomicAdd(&cursor[d], 1);
        eidx[p]  = s;
        enorm[p] = dinv[s] * dinv[d];
    }
}

// ---------------- GEMM: out[N,COLS] = xform(H)[N,128] @ W[128,COLS] ----------------
// XFORM applies per-feature h*scale+shift (previous layer's BN) on load.

template <int COLS, bool XFORM>
__global__ __launch_bounds__(256) void gemm_kernel(const float* __restrict__ H,
                                                   const float* __restrict__ W,
                                                   const float* __restrict__ scale,
                                                   const float* __restrict__ shift,
                                                   float* __restrict__ out, int N) {
    constexpr int K  = 128;
    constexpr int TC = COLS / 8;   // col-groups of 8 per thread
    constexpr int TR = 256 / TC;   // row-groups of 4 per thread
    constexpr int ROWS = TR * 4;
    constexpr int KC = 32;         // K chunk staged for W

    __shared__ float Hs[ROWS][K + 4];
    __shared__ float Wsc[KC * COLS];

    const int tid  = threadIdx.x;
    const int row0 = blockIdx.x * ROWS;

    // stage H tile (with optional BN transform), zero-pad rows >= N
    for (int idx = tid; idx < ROWS * (K / 4); idx += 256) {
        int r  = idx >> 5;          // /32 float4s per row
        int c4 = (idx & 31) * 4;
        float4 v = {0.f, 0.f, 0.f, 0.f};
        int gr = row0 + r;
        if (gr < N) v = *(const float4*)(H + (size_t)gr * K + c4);
        if (XFORM) {
            float4 sc = *(const float4*)(scale + c4);
            float4 sh = *(const float4*)(shift + c4);
            v.x = v.x * sc.x + sh.x;
            v.y = v.y * sc.y + sh.y;
            v.z = v.z * sc.z + sh.z;
            v.w = v.w * sc.w + sh.w;
        }
        *(float4*)&Hs[r][c4] = v;
    }

    const int tc = tid % TC, tr = tid / TC;
    const int r0 = tr * 4, c0 = tc * 8;

    float acc[4][8];
#pragma unroll
    for (int i = 0; i < 4; ++i)
#pragma unroll
        for (int j = 0; j < 8; ++j) acc[i][j] = 0.f;

    for (int kc = 0; kc < K; kc += KC) {
        __syncthreads();  // also guards initial Hs staging
        for (int idx = tid; idx < KC * COLS / 4; idx += 256)
            ((float4*)Wsc)[idx] = ((const float4*)(W + (size_t)kc * COLS))[idx];
        __syncthreads();
#pragma unroll
        for (int kk = 0; kk < KC; ++kk) {
            float a0 = Hs[r0 + 0][kc + kk];
            float a1 = Hs[r0 + 1][kc + kk];
            float a2 = Hs[r0 + 2][kc + kk];
            float a3 = Hs[r0 + 3][kc + kk];
            float w[8];
#pragma unroll
            for (int j = 0; j < 8; ++j) w[j] = Wsc[kk * COLS + c0 + j];
#pragma unroll
            for (int j = 0; j < 8; ++j) {
                acc[0][j] += a0 * w[j];
                acc[1][j] += a1 * w[j];
                acc[2][j] += a2 * w[j];
                acc[3][j] += a3 * w[j];
            }
        }
    }

#pragma unroll
    for (int i = 0; i < 4; ++i) {
        int r = row0 + r0 + i;
        if (r < N) {
            float4 o0 = {acc[i][0], acc[i][1], acc[i][2], acc[i][3]};
            float4 o1 = {acc[i][4], acc[i][5], acc[i][6], acc[i][7]};
            *(float4*)(out + (size_t)r * COLS + c0)     = o0;
            *(float4*)(out + (size_t)r * COLS + c0 + 4) = o1;
        }
    }
}

// ---------------- Aggregation: out = relu(D^-1/2 A D^-1/2 hw + b), fused BN stats ----------------

template <int F, bool STATS>
__global__ __launch_bounds__(256) void agg_kernel(const float* __restrict__ HW,
                                                  const int* __restrict__ rowptr,
                                                  const int* __restrict__ eidx,
                                                  const float* __restrict__ enorm,
                                                  const float* __restrict__ dinv,
                                                  const float* __restrict__ bias,
                                                  float* __restrict__ out,
                                                  float* __restrict__ stats, int N) {
    constexpr int TPR = F / 4;      // threads per row (float4 each)
    constexpr int RPB = 256 / TPR;  // rows per block per tile
    const int tid = threadIdx.x;
    const int lr  = tid / TPR;
    const int fc  = (tid % TPR) * 4;

    float4 ssum = {0.f, 0.f, 0.f, 0.f};
    float4 ssq  = {0.f, 0.f, 0.f, 0.f};

    const float4 b4 = *(const float4*)(bias + fc);

    for (int base = blockIdx.x * RPB; base < N; base += gridDim.x * RPB) {
        int row = base + lr;
        if (row < N) {
            float di = dinv[row];
            float4 v = *(const float4*)(HW + (size_t)row * F + fc);
            float w0 = di * di;  // self-loop norm
            float4 acc = {w0 * v.x, w0 * v.y, w0 * v.z, w0 * v.w};
            int j0 = rowptr[row], j1 = rowptr[row + 1];
            for (int j = j0; j < j1; ++j) {
                int   s = eidx[j];
                float w = enorm[j];
                float4 g = *(const float4*)(HW + (size_t)s * F + fc);
                acc.x += w * g.x; acc.y += w * g.y;
                acc.z += w * g.z; acc.w += w * g.w;
            }
            acc.x = fmaxf(acc.x + b4.x, 0.f);
            acc.y = fmaxf(acc.y + b4.y, 0.f);
            acc.z = fmaxf(acc.z + b4.z, 0.f);
            acc.w = fmaxf(acc.w + b4.w, 0.f);
            *(float4*)(out + (size_t)row * F + fc) = acc;
            if (STATS) {
                ssum.x += acc.x; ssum.y += acc.y; ssum.z += acc.z; ssum.w += acc.w;
                ssq.x += acc.x * acc.x; ssq.y += acc.y * acc.y;
                ssq.z += acc.z * acc.z; ssq.w += acc.w * acc.w;
            }
        }
    }

    if constexpr (STATS) {
        __shared__ float red[RPB][F];
        red[lr][fc + 0] = ssum.x; red[lr][fc + 1] = ssum.y;
        red[lr][fc + 2] = ssum.z; red[lr][fc + 3] = ssum.w;
        __syncthreads();
        if (tid < F) {
            float s = 0.f;
#pragma unroll
            for (int r = 0; r < RPB; ++r) s += red[r][tid];
            atomicAdd(&stats[tid], s);
        }
        __syncthreads();
        red[lr][fc + 0] = ssq.x; red[lr][fc + 1] = ssq.y;
        red[lr][fc + 2] = ssq.z; red[lr][fc + 3] = ssq.w;
        __syncthreads();
        if (tid < F) {
            float s = 0.f;
#pragma unroll
            for (int r = 0; r < RPB; ++r) s += red[r][tid];
            atomicAdd(&stats[F + tid], s);
        }
    }
}

__global__ void bn_fin_kernel(const float* __restrict__ stats, const float* __restrict__ g,
                              const float* __restrict__ be, float* __restrict__ scale,
                              float* __restrict__ shift, float invN) {
    int c = threadIdx.x;  // 128
    float mu  = stats[c] * invN;
    float var = stats[128 + c] * invN - mu * mu;
    float rs  = rsqrtf(var + BN_EPS);
    float sc  = rs * g[c];
    scale[c] = sc;
    shift[c] = be[c] - mu * sc;
}

// ---------------- launch ----------------

extern "C" void kernel_launch(void* const* d_in, const int* in_sizes, int n_in,
                              void* d_out, int out_size, void* d_ws, size_t ws_size,
                              hipStream_t stream) {
    const float* x  = (const float*)d_in[0];
    const int*   ei = (const int*)d_in[1];
    const float* W1 = (const float*)d_in[2];  const float* b1 = (const float*)d_in[3];
    const float* W2 = (const float*)d_in[4];  const float* b2 = (const float*)d_in[5];
    const float* W3 = (const float*)d_in[6];  const float* b3 = (const float*)d_in[7];
    const float* W4 = (const float*)d_in[8];  const float* b4 = (const float*)d_in[9];
    const float* g1 = (const float*)d_in[10]; const float* be1 = (const float*)d_in[11];
    const float* g2 = (const float*)d_in[12]; const float* be2 = (const float*)d_in[13];
    const float* g3 = (const float*)d_in[14]; const float* be3 = (const float*)d_in[15];

    const int N = in_sizes[0] / 128;
    const int E = in_sizes[1] / 2;
    const int nblk = (N + 1023) / 1024;

    size_t off = 0;
    char* ws = (char*)d_ws;
    auto alloc = [&](size_t bytes) -> void* {
        void* p = ws + off;
        off += (bytes + 255) & ~(size_t)255;
        return p;
    };
    int*   cnt    = (int*)alloc((size_t)N * 4);
    float* dinv   = (float*)alloc((size_t)N * 4);
    int*   rowptr = (int*)alloc((size_t)(N + 1) * 4);
    int*   cursor = (int*)alloc((size_t)N * 4);
    int*   bsum   = (int*)alloc((size_t)nblk * 4);
    int*   boff   = (int*)alloc((size_t)(nblk + 1) * 4);
    int*   eidx   = (int*)alloc((size_t)E * 4);
    float* enorm  = (float*)alloc((size_t)E * 4);
    float* stats  = (float*)alloc(256 * 4);
    float* scale  = (float*)alloc(128 * 4);
    float* shift  = (float*)alloc(128 * 4);
    float* buA    = (float*)alloc((size_t)N * 128 * 4);
    float* buB    = (float*)alloc((size_t)N * 128 * 4);
    (void)ws_size; (void)n_in; (void)out_size;

    const int TB = 256;
    const int gE = (E + TB - 1) / TB;
    const int gN = (N + TB - 1) / TB;

    // CSR + norm
    hipMemsetAsync(cnt, 0, (size_t)N * 4, stream);
    count_kernel<<<gE, TB, 0, stream>>>(ei, E, cnt);
    dinv_kernel<<<gN, TB, 0, stream>>>(cnt, dinv, N);
    scan_blocks<<<nblk, 1024, 0, stream>>>(cnt, rowptr, bsum, N);
    scan_carry<<<1, 1, 0, stream>>>(bsum, boff, nblk);
    scan_add<<<gN, TB, 0, stream>>>(rowptr, boff, cursor, N, nblk);
    fill_kernel<<<gE, TB, 0, stream>>>(ei, E, cursor, dinv, eidx, enorm);

    const int gG128 = (N + 63) / 64;    // gemm<128> blocks (64 rows each)
    const int gG64  = (N + 127) / 128;  // gemm<64> blocks (128 rows each)
    const int gA    = 1024;             // agg grid (grid-stride)
    const float invN = 1.0f / (float)N;

    // layer 1
    gemm_kernel<128, false><<<gG128, 256, 0, stream>>>(x, W1, nullptr, nullptr, buB, N);
    hipMemsetAsync(stats, 0, 256 * 4, stream);
    agg_kernel<128, true><<<gA, 256, 0, stream>>>(buB, rowptr, eidx, enorm, dinv, b1, buA, stats, N);
    bn_fin_kernel<<<1, 128, 0, stream>>>(stats, g1, be1, scale, shift, invN);

    // layer 2
    gemm_kernel<128, true><<<gG128, 256, 0, stream>>>(buA, W2, scale, shift, buB, N);
    hipMemsetAsync(stats, 0, 256 * 4, stream);
    agg_kernel<128, true><<<gA, 256, 0, stream>>>(buB, rowptr, eidx, enorm, dinv, b2, buA, stats, N);
    bn_fin_kernel<<<1, 128, 0, stream>>>(stats, g2, be2, scale, shift, invN);

    // layer 3
    gemm_kernel<128, true><<<gG128, 256, 0, stream>>>(buA, W3, scale, shift, buB, N);
    hipMemsetAsync(stats, 0, 256 * 4, stream);
    agg_kernel<128, true><<<gA, 256, 0, stream>>>(buB, rowptr, eidx, enorm, dinv, b3, buA, stats, N);
    bn_fin_kernel<<<1, 128, 0, stream>>>(stats, g3, be3, scale, shift, invN);

    // layer 4 (output D=64, no BN)
    gemm_kernel<64, true><<<gG64, 256, 0, stream>>>(buA, W4, scale, shift, buB, N);
    agg_kernel<64, false><<<gA, 256, 0, stream>>>(buB, rowptr, eidx, enorm, dinv, b4,
                                                  (float*)d_out, nullptr, N);
}

// Round 2
// 517.201 us; speedup vs baseline: 1.2551x; 1.2551x over previous
//
#include <hip/hip_runtime.h>

#define BN_EPS 1e-5f

using bfrag = __attribute__((ext_vector_type(8))) short;
using f32x4 = __attribute__((ext_vector_type(4))) float;

__device__ inline float bf2f(unsigned int h16) {
    union { unsigned int u; float f; } v; v.u = h16 << 16; return v.f;
}
__device__ inline unsigned short f2bf(float f) {
    union { float f; unsigned int u; } v; v.f = f;
    unsigned int u = v.u;
    u += 0x7fffu + ((u >> 16) & 1u);
    return (unsigned short)(u >> 16);
}
__device__ inline void unpack8(uint4 u, float* f) {
    f[0] = bf2f(u.x & 0xffffu); f[1] = bf2f(u.x >> 16);
    f[2] = bf2f(u.y & 0xffffu); f[3] = bf2f(u.y >> 16);
    f[4] = bf2f(u.z & 0xffffu); f[5] = bf2f(u.z >> 16);
    f[6] = bf2f(u.w & 0xffffu); f[7] = bf2f(u.w >> 16);
}

// ---------------- CSR build ----------------

__global__ void count_kernel(const int* __restrict__ ei, int E, int* __restrict__ cnt) {
    int e = blockIdx.x * blockDim.x + threadIdx.x;
    if (e < E) atomicAdd(&cnt[ei[E + e]], 1);
}

__global__ void dinv_kernel(const int* __restrict__ cnt, float* __restrict__ dinv, int N) {
    int i = blockIdx.x * blockDim.x + threadIdx.x;
    if (i < N) dinv[i] = rsqrtf((float)(cnt[i] + 1));  // +1 self loop
}

__global__ __launch_bounds__(1024) void scan_blocks(const int* __restrict__ cnt,
                                                    int* __restrict__ rowptr,
                                                    int* __restrict__ bsum, int N) {
    __shared__ int sh[1024];
    int t = threadIdx.x;
    int i = blockIdx.x * 1024 + t;
    int v = (i < N) ? cnt[i] : 0;
    sh[t] = v;
    __syncthreads();
    for (int off = 1; off < 1024; off <<= 1) {
        int x = (t >= off) ? sh[t - off] : 0;
        __syncthreads();
        sh[t] += x;
        __syncthreads();
    }
    if (i < N) rowptr[i] = sh[t] - v;
    if (t == 1023) bsum[blockIdx.x] = sh[1023];
}

__global__ void scan_carry(const int* __restrict__ bsum, int* __restrict__ boff, int nblk) {
    if (threadIdx.x == 0 && blockIdx.x == 0) {
        int run = 0;
        for (int b = 0; b < nblk; ++b) { int v = bsum[b]; boff[b] = run; run += v; }
        boff[nblk] = run;
    }
}

__global__ void scan_add(int* __restrict__ rowptr, const int* __restrict__ boff,
                         int* __restrict__ cursor, int N, int nblk) {
    int i = blockIdx.x * blockDim.x + threadIdx.x;
    if (i < N) {
        int v = rowptr[i] + boff[i >> 10];
        rowptr[i] = v;
        cursor[i] = v;
    }
    if (i == 0) rowptr[N] = boff[nblk];
}

__global__ void fill_kernel(const int* __restrict__ ei, int E, int* __restrict__ cursor,
                            const float* __restrict__ dinv, int* __restrict__ eidx,
                            float* __restrict__ enorm) {
    int e = blockIdx.x * blockDim.x + threadIdx.x;
    if (e < E) {
        int s = ei[e], d = ei[E + e];
        int p = atomicAdd(&cursor[d], 1);
        eidx[p]  = s;
        enorm[p] = dinv[s] * dinv[d];
    }
}

__global__ void s_kernel(const int* __restrict__ rowptr, const float* __restrict__ enorm,
                         const float* __restrict__ dinv, float* __restrict__ sarr, int N) {
    int i = blockIdx.x * blockDim.x + threadIdx.x;
    if (i < N) {
        float a = dinv[i] * dinv[i];
        int j1 = rowptr[i + 1];
        for (int j = rowptr[i]; j < j1; ++j) a += enorm[j];
        sarr[i] = a;
    }
}

// ---------------- per-layer weight prep: Wt[j][k] = bf16(scale[k]*W[k][j]), c[j]=shift@W ----------------

template <bool HASBN>
__global__ __launch_bounds__(256) void prep_kernel(const float* __restrict__ W, int COLS,
                                                   const float* __restrict__ stats,
                                                   const float* __restrict__ g,
                                                   const float* __restrict__ be, float invN,
                                                   unsigned short* __restrict__ Wt,
                                                   float* __restrict__ cvec) {
    __shared__ float sc[128], sh[128];
    int tid = threadIdx.x;
    if (tid < 128) {
        if (HASBN) {
            float mu  = stats[tid] * invN;
            float var = stats[128 + tid] * invN - mu * mu;
            float rs  = rsqrtf(var + BN_EPS);
            float s   = rs * g[tid];
            sc[tid] = s;
            sh[tid] = be[tid] - mu * s;
        } else { sc[tid] = 1.f; sh[tid] = 0.f; }
    }
    __syncthreads();
    int total = 128 * COLS;
    for (int idx = blockIdx.x * 256 + tid; idx < total; idx += gridDim.x * 256) {
        int k = idx / COLS, j = idx % COLS;
        Wt[j * 128 + k] = f2bf(sc[k] * W[idx]);
    }
    if (blockIdx.x == 0 && tid < COLS) {
        float a = 0.f;
        if (HASBN)
            for (int k = 0; k < 128; ++k) a += sh[k] * W[k * COLS + tid];
        cvec[tid] = a;
    }
}

// ---------------- GEMM: out[N,COLS](bf16) = H[N,128] @ Wt^T, MFMA bf16 ----------------

template <int COLS, bool IN_F32>
__global__ __launch_bounds__(256) void gemm_mfma(const void* __restrict__ Hin,
                                                 const unsigned short* __restrict__ Wt,
                                                 unsigned short* __restrict__ out, int N) {
    __shared__ unsigned short Hs[64][136];
    const int tid  = threadIdx.x;
    const int row0 = blockIdx.x * 64;

    if (IN_F32) {
        const float* H = (const float*)Hin;
#pragma unroll
        for (int it = 0; it < 8; ++it) {
            int idx = it * 256 + tid;
            int r = idx >> 5, c4 = (idx & 31) * 4;
            float4 v = {0.f, 0.f, 0.f, 0.f};
            if (row0 + r < N) v = *(const float4*)(H + (size_t)(row0 + r) * 128 + c4);
            Hs[r][c4 + 0] = f2bf(v.x); Hs[r][c4 + 1] = f2bf(v.y);
            Hs[r][c4 + 2] = f2bf(v.z); Hs[r][c4 + 3] = f2bf(v.w);
        }
    } else {
        const unsigned short* H = (const unsigned short*)Hin;
#pragma unroll
        for (int it = 0; it < 4; ++it) {
            int idx = it * 256 + tid;
            int r = idx >> 4, c8 = (idx & 15) * 8;
            uint4 v = {0u, 0u, 0u, 0u};
            if (row0 + r < N) v = *(const uint4*)(H + (size_t)(row0 + r) * 128 + c8);
            *(uint4*)&Hs[r][c8] = v;
        }
    }
    __syncthreads();

    const int lane = tid & 63, wave = tid >> 6;
    const int arow = lane & 15, kg = lane >> 4;
    const int r0   = wave * 16;

    bfrag af[4];
#pragma unroll
    for (int kc = 0; kc < 4; ++kc) af[kc] = *(const bfrag*)&Hs[r0 + arow][kc * 32 + kg * 8];

    constexpr int NT = COLS / 16;
    f32x4 acc[NT];
#pragma unroll
    for (int nt = 0; nt < NT; ++nt) acc[nt] = (f32x4){0.f, 0.f, 0.f, 0.f};

#pragma unroll
    for (int nt = 0; nt < NT; ++nt) {
        const unsigned short* wp = Wt + (size_t)(nt * 16 + arow) * 128 + kg * 8;
#pragma unroll
        for (int kc = 0; kc < 4; ++kc) {
            bfrag bf = *(const bfrag*)(wp + kc * 32);
            acc[nt] = __builtin_amdgcn_mfma_f32_16x16x32_bf16(af[kc], bf, acc[nt], 0, 0, 0);
        }
    }
    __syncthreads();

#pragma unroll
    for (int nt = 0; nt < NT; ++nt) {
        int col = nt * 16 + arow;
#pragma unroll
        for (int r = 0; r < 4; ++r)
            Hs[r0 + kg * 4 + r][col] = f2bf(acc[nt][r]);
    }
    __syncthreads();

    constexpr int CH = COLS / 8;
    for (int idx = tid; idx < 64 * CH; idx += 256) {
        int r = idx / CH, c8 = (idx % CH) * 8;
        if (row0 + r < N)
            *(uint4*)(out + (size_t)(row0 + r) * COLS + c8) = *(const uint4*)&Hs[r][c8];
    }
}

// ---------------- Aggregation: out = relu(agg(hw) + c*s + b), fused BN stats ----------------

template <int F, bool STATS, bool HASC, typename TOUT>
__global__ __launch_bounds__(256) void agg_kernel(const unsigned short* __restrict__ HW,
                                                  const int* __restrict__ rowptr,
                                                  const int* __restrict__ eidx,
                                                  const float* __restrict__ enorm,
                                                  const float* __restrict__ dinv,
                                                  const float* __restrict__ sarr,
                                                  const float* __restrict__ cvec,
                                                  const float* __restrict__ bias,
                                                  TOUT* __restrict__ out,
                                                  float* __restrict__ stats, int N) {
    constexpr int TPR = F / 8;      // threads per row (8 bf16 = 16B each)
    constexpr int RPB = 256 / TPR;  // rows per block per tile
    const int tid = threadIdx.x;
    const int lr  = tid / TPR;
    const int j8  = (tid % TPR) * 8;

    float b8[8], c8[8];
#pragma unroll
    for (int k = 0; k < 8; ++k) b8[k] = bias[j8 + k];
    if (HASC) {
#pragma unroll
        for (int k = 0; k < 8; ++k) c8[k] = cvec[j8 + k];
    }

    float ssum[8], ssq[8];
#pragma unroll
    for (int k = 0; k < 8; ++k) { ssum[k] = 0.f; ssq[k] = 0.f; }

    for (int base = blockIdx.x * RPB; base < N; base += gridDim.x * RPB) {
        int row = base + lr;
        if (row < N) {
            float di = dinv[row];
            float w0 = di * di;
            float acc[8], v[8];
            uint4 u = *(const uint4*)(HW + (size_t)row * F + j8);
            unpack8(u, v);
#pragma unroll
            for (int k = 0; k < 8; ++k) acc[k] = w0 * v[k];
            int j0 = rowptr[row], j1 = rowptr[row + 1];
            for (int j = j0; j < j1; ++j) {
                int   s = eidx[j];
                float w = enorm[j];
                uint4 gu = *(const uint4*)(HW + (size_t)s * F + j8);
                unpack8(gu, v);
#pragma unroll
                for (int k = 0; k < 8; ++k) acc[k] += w * v[k];
            }
            if (HASC) {
                float sv = sarr[row];
#pragma unroll
                for (int k = 0; k < 8; ++k) acc[k] += c8[k] * sv;
            }
#pragma unroll
            for (int k = 0; k < 8; ++k) acc[k] = fmaxf(acc[k] + b8[k], 0.f);

            if constexpr (sizeof(TOUT) == 2) {
                unsigned int w0b = (unsigned int)f2bf(acc[0]) | ((unsigned int)f2bf(acc[1]) << 16);
                unsigned int w1b = (unsigned int)f2bf(acc[2]) | ((unsigned int)f2bf(acc[3]) << 16);
                unsigned int w2b = (unsigned int)f2bf(acc[4]) | ((unsigned int)f2bf(acc[5]) << 16);
                unsigned int w3b = (unsigned int)f2bf(acc[6]) | ((unsigned int)f2bf(acc[7]) << 16);
                uint4 o = {w0b, w1b, w2b, w3b};
                *(uint4*)((unsigned short*)out + (size_t)row * F + j8) = o;
            } else {
                float4 o0 = {acc[0], acc[1], acc[2], acc[3]};
                float4 o1 = {acc[4], acc[5], acc[6], acc[7]};
                *(float4*)((float*)out + (size_t)row * F + j8)     = o0;
                *(float4*)((float*)out + (size_t)row * F + j8 + 4) = o1;
            }
            if (STATS) {
#pragma unroll
                for (int k = 0; k < 8; ++k) {
                    ssum[k] += acc[k];
                    ssq[k]  += acc[k] * acc[k];
                }
            }
        }
    }

    if constexpr (STATS) {
        __shared__ float red[RPB][F];
#pragma unroll
        for (int k = 0; k < 8; ++k) red[lr][j8 + k] = ssum[k];
        __syncthreads();
        if (tid < F) {
            float a = 0.f;
#pragma unroll
            for (int r = 0; r < RPB; ++r) a += red[r][tid];
            atomicAdd(&stats[tid], a);
        }
        __syncthreads();
#pragma unroll
        for (int k = 0; k < 8; ++k) red[lr][j8 + k] = ssq[k];
        __syncthreads();
        if (tid < F) {
            float a = 0.f;
#pragma unroll
            for (int r = 0; r < RPB; ++r) a += red[r][tid];
            atomicAdd(&stats[F + tid], a);
        }
    }
}

// ---------------- launch ----------------

extern "C" void kernel_launch(void* const* d_in, const int* in_sizes, int n_in,
                              void* d_out, int out_size, void* d_ws, size_t ws_size,
                              hipStream_t stream) {
    const float* x  = (const float*)d_in[0];
    const int*   ei = (const int*)d_in[1];
    const float* W1 = (const float*)d_in[2];  const float* b1 = (const float*)d_in[3];
    const float* W2 = (const float*)d_in[4];  const float* b2 = (const float*)d_in[5];
    const float* W3 = (const float*)d_in[6];  const float* b3 = (const float*)d_in[7];
    const float* W4 = (const float*)d_in[8];  const float* b4 = (const float*)d_in[9];
    const float* g1 = (const float*)d_in[10]; const float* be1 = (const float*)d_in[11];
    const float* g2 = (const float*)d_in[12]; const float* be2 = (const float*)d_in[13];
    const float* g3 = (const float*)d_in[14]; const float* be3 = (const float*)d_in[15];

    const int N = in_sizes[0] / 128;
    const int E = in_sizes[1] / 2;
    const int nblk = (N + 1023) / 1024;

    size_t off = 0;
    char* ws = (char*)d_ws;
    auto alloc = [&](size_t bytes) -> void* {
        void* p = ws + off;
        off += (bytes + 255) & ~(size_t)255;
        return p;
    };
    int*   cnt    = (int*)alloc((size_t)N * 4);
    float* dinv   = (float*)alloc((size_t)N * 4);
    int*   rowptr = (int*)alloc((size_t)(N + 1) * 4);
    int*   cursor = (int*)alloc((size_t)N * 4);
    int*   bsum   = (int*)alloc((size_t)nblk * 4);
    int*   boff   = (int*)alloc((size_t)(nblk + 1) * 4);
    int*   eidx   = (int*)alloc((size_t)E * 4);
    float* enorm  = (float*)alloc((size_t)E * 4);
    float* sarr   = (float*)alloc((size_t)N * 4);
    float* stats  = (float*)alloc(256 * 4);
    unsigned short* Wt = (unsigned short*)alloc(128 * 128 * 2);
    float* cvec   = (float*)alloc(128 * 4);
    unsigned short* hA  = (unsigned short*)alloc((size_t)N * 128 * 2);
    unsigned short* hwB = (unsigned short*)alloc((size_t)N * 128 * 2);
    (void)ws_size; (void)n_in; (void)out_size;

    const int TB = 256;
    const int gE = (E + TB - 1) / TB;
    const int gN = (N + TB - 1) / TB;

    // CSR + norm + s[]
    hipMemsetAsync(cnt, 0, (size_t)N * 4, stream);
    count_kernel<<<gE, TB, 0, stream>>>(ei, E, cnt);
    dinv_kernel<<<gN, TB, 0, stream>>>(cnt, dinv, N);
    scan_blocks<<<nblk, 1024, 0, stream>>>(cnt, rowptr, bsum, N);
    scan_carry<<<1, 1, 0, stream>>>(bsum, boff, nblk);
    scan_add<<<gN, TB, 0, stream>>>(rowptr, boff, cursor, N, nblk);
    fill_kernel<<<gE, TB, 0, stream>>>(ei, E, cursor, dinv, eidx, enorm);
    s_kernel<<<gN, TB, 0, stream>>>(rowptr, enorm, dinv, sarr, N);

    const int gG  = (N + 63) / 64;
    const int gA  = 2048;
    const float invN = 1.0f / (float)N;

    // layer 1 (no BN fold; c=0)
    prep_kernel<false><<<8, 256, 0, stream>>>(W1, 128, nullptr, nullptr, nullptr, 0.f, Wt, cvec);
    gemm_mfma<128, true><<<gG, 256, 0, stream>>>(x, Wt, hwB, N);
    hipMemsetAsync(stats, 0, 256 * 4, stream);
    agg_kernel<128, true, false, unsigned short><<<gA, 256, 0, stream>>>(
        hwB, rowptr, eidx, enorm, dinv, sarr, cvec, b1, hA, stats, N);

    // layer 2
    prep_kernel<true><<<8, 256, 0, stream>>>(W2, 128, stats, g1, be1, invN, Wt, cvec);
    gemm_mfma<128, false><<<gG, 256, 0, stream>>>(hA, Wt, hwB, N);
    hipMemsetAsync(stats, 0, 256 * 4, stream);
    agg_kernel<128, true, true, unsigned short><<<gA, 256, 0, stream>>>(
        hwB, rowptr, eidx, enorm, dinv, sarr, cvec, b2, hA, stats, N);

    // layer 3
    prep_kernel<true><<<8, 256, 0, stream>>>(W3, 128, stats, g2, be2, invN, Wt, cvec);
    gemm_mfma<128, false><<<gG, 256, 0, stream>>>(hA, Wt, hwB, N);
    hipMemsetAsync(stats, 0, 256 * 4, stream);
    agg_kernel<128, true, true, unsigned short><<<gA, 256, 0, stream>>>(
        hwB, rowptr, eidx, enorm, dinv, sarr, cvec, b3, hA, stats, N);

    // layer 4 (COLS=64, f32 out, no stats)
    prep_kernel<true><<<8, 256, 0, stream>>>(W4, 64, stats, g3, be3, invN, Wt, cvec);
    gemm_mfma<64, false><<<gG, 256, 0, stream>>>(hA, Wt, hwB, N);
    agg_kernel<64, false, true, float><<<gA, 256, 0, stream>>>(
        hwB, rowptr, eidx, enorm, dinv, sarr, cvec, b4, (float*)d_out, nullptr, N);
}

// Round 3
// 490.803 us; speedup vs baseline: 1.3226x; 1.0538x over previous
//
#include <hip/hip_runtime.h>

#define BN_EPS 1e-5f

using bfrag = __attribute__((ext_vector_type(8))) short;
using f32x4 = __attribute__((ext_vector_type(4))) float;

__device__ inline float bf2f(unsigned int h16) {
    union { unsigned int u; float f; } v; v.u = h16 << 16; return v.f;
}
__device__ inline unsigned short f2bf(float f) {
    union { float f; unsigned int u; } v; v.f = f;
    unsigned int u = v.u;
    u += 0x7fffu + ((u >> 16) & 1u);
    return (unsigned short)(u >> 16);
}
__device__ inline void unpack8(uint4 u, float* f) {
    f[0] = bf2f(u.x & 0xffffu); f[1] = bf2f(u.x >> 16);
    f[2] = bf2f(u.y & 0xffffu); f[3] = bf2f(u.y >> 16);
    f[4] = bf2f(u.z & 0xffffu); f[5] = bf2f(u.z >> 16);
    f[6] = bf2f(u.w & 0xffffu); f[7] = bf2f(u.w >> 16);
}

// ---------------- CSR build ----------------

__global__ void count_kernel(const int* __restrict__ ei, int E, int* __restrict__ cnt) {
    int e = blockIdx.x * blockDim.x + threadIdx.x;
    if (e < E) atomicAdd(&cnt[ei[E + e]], 1);
}

__global__ void dinv_kernel(const int* __restrict__ cnt, float* __restrict__ dinv, int N) {
    int i = blockIdx.x * blockDim.x + threadIdx.x;
    if (i < N) dinv[i] = rsqrtf((float)(cnt[i] + 1));  // +1 self loop
}

__global__ __launch_bounds__(1024) void scan_blocks(const int* __restrict__ cnt,
                                                    int* __restrict__ rowptr,
                                                    int* __restrict__ bsum, int N) {
    __shared__ int sh[1024];
    int t = threadIdx.x;
    int i = blockIdx.x * 1024 + t;
    int v = (i < N) ? cnt[i] : 0;
    sh[t] = v;
    __syncthreads();
    for (int off = 1; off < 1024; off <<= 1) {
        int x = (t >= off) ? sh[t - off] : 0;
        __syncthreads();
        sh[t] += x;
        __syncthreads();
    }
    if (i < N) rowptr[i] = sh[t] - v;
    if (t == 1023) bsum[blockIdx.x] = sh[1023];
}

__global__ void scan_carry(const int* __restrict__ bsum, int* __restrict__ boff, int nblk) {
    if (threadIdx.x == 0 && blockIdx.x == 0) {
        int run = 0;
        for (int b = 0; b < nblk; ++b) { int v = bsum[b]; boff[b] = run; run += v; }
        boff[nblk] = run;
    }
}

__global__ void scan_add(int* __restrict__ rowptr, const int* __restrict__ boff,
                         int* __restrict__ cursor, int N, int nblk) {
    int i = blockIdx.x * blockDim.x + threadIdx.x;
    if (i < N) {
        int v = rowptr[i] + boff[i >> 10];
        rowptr[i] = v;
        cursor[i] = v;
    }
    if (i == 0) rowptr[N] = boff[nblk];
}

__global__ void fill_kernel(const int* __restrict__ ei, int E, int* __restrict__ cursor,
                            const float* __restrict__ dinv, int2* __restrict__ epack) {
    int e = blockIdx.x * blockDim.x + threadIdx.x;
    if (e < E) {
        int s = ei[e], d = ei[E + e];
        int p = atomicAdd(&cursor[d], 1);
        float nrm = dinv[s] * dinv[d];
        epack[p] = make_int2(s, __float_as_int(nrm));
    }
}

__global__ void s_kernel(const int* __restrict__ rowptr, const int2* __restrict__ epack,
                         const float* __restrict__ dinv, float* __restrict__ sarr, int N) {
    int i = blockIdx.x * blockDim.x + threadIdx.x;
    if (i < N) {
        float a = dinv[i] * dinv[i];
        int j1 = rowptr[i + 1];
        for (int j = rowptr[i]; j < j1; ++j) a += __int_as_float(epack[j].y);
        sarr[i] = a;
    }
}

// ---------------- per-layer weight prep: Wt[j][k] = bf16(scale[k]*W[k][j]), c[j]=shift@W ----------------

template <bool HASBN>
__global__ __launch_bounds__(256) void prep_kernel(const float* __restrict__ W, int COLS,
                                                   const float* __restrict__ stats,
                                                   const float* __restrict__ g,
                                                   const float* __restrict__ be, float invN,
                                                   unsigned short* __restrict__ Wt,
                                                   float* __restrict__ cvec) {
    __shared__ float sc[128], sh[128];
    int tid = threadIdx.x;
    if (tid < 128) {
        if (HASBN) {
            float mu  = stats[tid] * invN;
            float var = stats[128 + tid] * invN - mu * mu;
            float rs  = rsqrtf(var + BN_EPS);
            float s   = rs * g[tid];
            sc[tid] = s;
            sh[tid] = be[tid] - mu * s;
        } else { sc[tid] = 1.f; sh[tid] = 0.f; }
    }
    __syncthreads();
    int total = 128 * COLS;
    for (int idx = blockIdx.x * 256 + tid; idx < total; idx += gridDim.x * 256) {
        int k = idx / COLS, j = idx % COLS;
        Wt[j * 128 + k] = f2bf(sc[k] * W[idx]);
    }
    if (blockIdx.x == 0 && tid < COLS) {
        float a = 0.f;
        if (HASBN)
            for (int k = 0; k < 128; ++k) a += sh[k] * W[k * COLS + tid];
        cvec[tid] = a;
    }
}

// ---------------- GEMM: out[N,COLS](bf16) = H[N,128] @ Wt^T, MFMA bf16 ----------------

template <int COLS, bool IN_F32>
__global__ __launch_bounds__(256) void gemm_mfma(const void* __restrict__ Hin,
                                                 const unsigned short* __restrict__ Wt,
                                                 unsigned short* __restrict__ out, int N) {
    __shared__ unsigned short Hs[64][136];
    const int tid  = threadIdx.x;
    const int row0 = blockIdx.x * 64;

    if (IN_F32) {
        const float* H = (const float*)Hin;
#pragma unroll
        for (int it = 0; it < 8; ++it) {
            int idx = it * 256 + tid;
            int r = idx >> 5, c4 = (idx & 31) * 4;
            float4 v = {0.f, 0.f, 0.f, 0.f};
            if (row0 + r < N) v = *(const float4*)(H + (size_t)(row0 + r) * 128 + c4);
            Hs[r][c4 + 0] = f2bf(v.x); Hs[r][c4 + 1] = f2bf(v.y);
            Hs[r][c4 + 2] = f2bf(v.z); Hs[r][c4 + 3] = f2bf(v.w);
        }
    } else {
        const unsigned short* H = (const unsigned short*)Hin;
#pragma unroll
        for (int it = 0; it < 4; ++it) {
            int idx = it * 256 + tid;
            int r = idx >> 4, c8 = (idx & 15) * 8;
            uint4 v = {0u, 0u, 0u, 0u};
            if (row0 + r < N) v = *(const uint4*)(H + (size_t)(row0 + r) * 128 + c8);
            *(uint4*)&Hs[r][c8] = v;
        }
    }
    __syncthreads();

    const int lane = tid & 63, wave = tid >> 6;
    const int arow = lane & 15, kg = lane >> 4;
    const int r0   = wave * 16;

    bfrag af[4];
#pragma unroll
    for (int kc = 0; kc < 4; ++kc) af[kc] = *(const bfrag*)&Hs[r0 + arow][kc * 32 + kg * 8];

    constexpr int NT = COLS / 16;
    f32x4 acc[NT];
#pragma unroll
    for (int nt = 0; nt < NT; ++nt) acc[nt] = (f32x4){0.f, 0.f, 0.f, 0.f};

#pragma unroll
    for (int nt = 0; nt < NT; ++nt) {
        const unsigned short* wp = Wt + (size_t)(nt * 16 + arow) * 128 + kg * 8;
#pragma unroll
        for (int kc = 0; kc < 4; ++kc) {
            bfrag bf = *(const bfrag*)(wp + kc * 32);
            acc[nt] = __builtin_amdgcn_mfma_f32_16x16x32_bf16(af[kc], bf, acc[nt], 0, 0, 0);
        }
    }
    __syncthreads();

#pragma unroll
    for (int nt = 0; nt < NT; ++nt) {
        int col = nt * 16 + arow;
#pragma unroll
        for (int r = 0; r < 4; ++r)
            Hs[r0 + kg * 4 + r][col] = f2bf(acc[nt][r]);
    }
    __syncthreads();

    constexpr int CH = COLS / 8;
    for (int idx = tid; idx < 64 * CH; idx += 256) {
        int r = idx / CH, c8 = (idx % CH) * 8;
        if (row0 + r < N)
            *(uint4*)(out + (size_t)(row0 + r) * COLS + c8) = *(const uint4*)&Hs[r][c8];
    }
}

// ---------------- Aggregation: out = relu(agg(hw) + c*s + b), fused BN stats ----------------
// 16 (or 8) lanes per row; edge records preloaded per-batch into registers, broadcast by shfl;
// gathers software-pipelined depth 2 for MLP.

template <int F, bool STATS, bool HASC, typename TOUT>
__global__ __launch_bounds__(256) void agg_kernel(const unsigned short* __restrict__ HW,
                                                  const int* __restrict__ rowptr,
                                                  const int2* __restrict__ epack,
                                                  const float* __restrict__ dinv,
                                                  const float* __restrict__ sarr,
                                                  const float* __restrict__ cvec,
                                                  const float* __restrict__ bias,
                                                  TOUT* __restrict__ out,
                                                  float* __restrict__ stats, int N) {
    constexpr int TPR = F / 8;      // lanes per row
    constexpr int RPB = 256 / TPR;  // rows per block tile
    const int tid = threadIdx.x;
    const int lr  = tid / TPR;
    const int fo  = tid % TPR;
    const int j8  = fo * 8;
    const int lanebase = (tid & 63) & ~(TPR - 1);

    float ssum[8], ssq[8];
    if (STATS) {
#pragma unroll
        for (int k = 0; k < 8; ++k) { ssum[k] = 0.f; ssq[k] = 0.f; }
    }

    for (int base = blockIdx.x * RPB; base < N; base += gridDim.x * RPB) {
        int row = base + lr;
        if (row < N) {
            float di = dinv[row];
            float w0 = di * di;
            float acc[8], v[8];
            uint4 u = *(const uint4*)(HW + (size_t)row * F + j8);
            unpack8(u, v);
#pragma unroll
            for (int k = 0; k < 8; ++k) acc[k] = w0 * v[k];

            const int j0 = rowptr[row], j1 = rowptr[row + 1];
            for (int jb = j0; jb < j1; jb += TPR) {
                int myj = jb + fo;
                int2 ep = (myj < j1) ? epack[myj] : make_int2(0, 0);
                int cnt = min(j1 - jb, TPR);
                // pipeline prologue: edge 0
                int   s0 = __shfl(ep.x, lanebase);
                float g0 = __int_as_float(__shfl(ep.y, lanebase));
                uint4 G0 = *(const uint4*)(HW + (size_t)s0 * F + j8);
                for (int t = 0; t < cnt; ++t) {
                    int tn = (t + 1 < cnt) ? t + 1 : t;   // clamp: dup load, never consumed
                    int   s1 = __shfl(ep.x, lanebase + tn);
                    float g1 = __int_as_float(__shfl(ep.y, lanebase + tn));
                    uint4 G1 = *(const uint4*)(HW + (size_t)s1 * F + j8);
                    unpack8(G0, v);
#pragma unroll
                    for (int k = 0; k < 8; ++k) acc[k] += g0 * v[k];
                    G0 = G1; g0 = g1;
                }
            }

            if (HASC) {
                float sv = sarr[row];
#pragma unroll
                for (int k = 0; k < 8; ++k) acc[k] += cvec[j8 + k] * sv;
            }
#pragma unroll
            for (int k = 0; k < 8; ++k) acc[k] = fmaxf(acc[k] + bias[j8 + k], 0.f);

            if constexpr (sizeof(TOUT) == 2) {
                unsigned int w0b = (unsigned int)f2bf(acc[0]) | ((unsigned int)f2bf(acc[1]) << 16);
                unsigned int w1b = (unsigned int)f2bf(acc[2]) | ((unsigned int)f2bf(acc[3]) << 16);
                unsigned int w2b = (unsigned int)f2bf(acc[4]) | ((unsigned int)f2bf(acc[5]) << 16);
                unsigned int w3b = (unsigned int)f2bf(acc[6]) | ((unsigned int)f2bf(acc[7]) << 16);
                uint4 o = {w0b, w1b, w2b, w3b};
                *(uint4*)((unsigned short*)out + (size_t)row * F + j8) = o;
            } else {
                float4 o0 = {acc[0], acc[1], acc[2], acc[3]};
                float4 o1 = {acc[4], acc[5], acc[6], acc[7]};
                *(float4*)((float*)out + (size_t)row * F + j8)     = o0;
                *(float4*)((float*)out + (size_t)row * F + j8 + 4) = o1;
            }
            if (STATS) {
#pragma unroll
                for (int k = 0; k < 8; ++k) {
                    ssum[k] += acc[k];
                    ssq[k]  += acc[k] * acc[k];
                }
            }
        }
    }

    if constexpr (STATS) {
        __shared__ float red[RPB][F];
#pragma unroll
        for (int k = 0; k < 8; ++k) red[lr][j8 + k] = ssum[k];
        __syncthreads();
        if (tid < F) {
            float a = 0.f;
#pragma unroll
            for (int r = 0; r < RPB; ++r) a += red[r][tid];
            atomicAdd(&stats[tid], a);
        }
        __syncthreads();
#pragma unroll
        for (int k = 0; k < 8; ++k) red[lr][j8 + k] = ssq[k];
        __syncthreads();
        if (tid < F) {
            float a = 0.f;
#pragma unroll
            for (int r = 0; r < RPB; ++r) a += red[r][tid];
            atomicAdd(&stats[F + tid], a);
        }
    }
}

// ---------------- launch ----------------

extern "C" void kernel_launch(void* const* d_in, const int* in_sizes, int n_in,
                              void* d_out, int out_size, void* d_ws, size_t ws_size,
                              hipStream_t stream) {
    const float* x  = (const float*)d_in[0];
    const int*   ei = (const int*)d_in[1];
    const float* W1 = (const float*)d_in[2];  const float* b1 = (const float*)d_in[3];
    const float* W2 = (const float*)d_in[4];  const float* b2 = (const float*)d_in[5];
    const float* W3 = (const float*)d_in[6];  const float* b3 = (const float*)d_in[7];
    const float* W4 = (const float*)d_in[8];  const float* b4 = (const float*)d_in[9];
    const float* g1 = (const float*)d_in[10]; const float* be1 = (const float*)d_in[11];
    const float* g2 = (const float*)d_in[12]; const float* be2 = (const float*)d_in[13];
    const float* g3 = (const float*)d_in[14]; const float* be3 = (const float*)d_in[15];

    const int N = in_sizes[0] / 128;
    const int E = in_sizes[1] / 2;
    const int nblk = (N + 1023) / 1024;

    size_t off = 0;
    char* ws = (char*)d_ws;
    auto alloc = [&](size_t bytes) -> void* {
        void* p = ws + off;
        off += (bytes + 255) & ~(size_t)255;
        return p;
    };
    int*   cnt    = (int*)alloc((size_t)N * 4);
    float* dinv   = (float*)alloc((size_t)N * 4);
    int*   rowptr = (int*)alloc((size_t)(N + 1) * 4);
    int*   cursor = (int*)alloc((size_t)N * 4);
    int*   bsum   = (int*)alloc((size_t)nblk * 4);
    int*   boff   = (int*)alloc((size_t)(nblk + 1) * 4);
    int2*  epack  = (int2*)alloc((size_t)E * 8);
    float* sarr   = (float*)alloc((size_t)N * 4);
    float* stats  = (float*)alloc(256 * 4);
    unsigned short* Wt = (unsigned short*)alloc(128 * 128 * 2);
    float* cvec   = (float*)alloc(128 * 4);
    unsigned short* hA  = (unsigned short*)alloc((size_t)N * 128 * 2);
    unsigned short* hwB = (unsigned short*)alloc((size_t)N * 128 * 2);
    (void)ws_size; (void)n_in; (void)out_size;

    const int TB = 256;
    const int gE = (E + TB - 1) / TB;
    const int gN = (N + TB - 1) / TB;

    // CSR + norm + s[]
    hipMemsetAsync(cnt, 0, (size_t)N * 4, stream);
    count_kernel<<<gE, TB, 0, stream>>>(ei, E, cnt);
    dinv_kernel<<<gN, TB, 0, stream>>>(cnt, dinv, N);
    scan_blocks<<<nblk, 1024, 0, stream>>>(cnt, rowptr, bsum, N);
    scan_carry<<<1, 1, 0, stream>>>(bsum, boff, nblk);
    scan_add<<<gN, TB, 0, stream>>>(rowptr, boff, cursor, N, nblk);
    fill_kernel<<<gE, TB, 0, stream>>>(ei, E, cursor, dinv, epack);
    s_kernel<<<gN, TB, 0, stream>>>(rowptr, epack, dinv, sarr, N);

    const int gG  = (N + 63) / 64;
    const int gA  = 2048;
    const float invN = 1.0f / (float)N;

    // layer 1 (no BN fold; c=0)
    prep_kernel<false><<<8, 256, 0, stream>>>(W1, 128, nullptr, nullptr, nullptr, 0.f, Wt, cvec);
    gemm_mfma<128, true><<<gG, 256, 0, stream>>>(x, Wt, hwB, N);
    hipMemsetAsync(stats, 0, 256 * 4, stream);
    agg_kernel<128, true, false, unsigned short><<<gA, 256, 0, stream>>>(
        hwB, rowptr, epack, dinv, sarr, cvec, b1, hA, stats, N);

    // layer 2
    prep_kernel<true><<<8, 256, 0, stream>>>(W2, 128, stats, g1, be1, invN, Wt, cvec);
    gemm_mfma<128, false><<<gG, 256, 0, stream>>>(hA, Wt, hwB, N);
    hipMemsetAsync(stats, 0, 256 * 4, stream);
    agg_kernel<128, true, true, unsigned short><<<gA, 256, 0, stream>>>(
        hwB, rowptr, epack, dinv, sarr, cvec, b2, hA, stats, N);

    // layer 3
    prep_kernel<true><<<8, 256, 0, stream>>>(W3, 128, stats, g2, be2, invN, Wt, cvec);
    gemm_mfma<128, false><<<gG, 256, 0, stream>>>(hA, Wt, hwB, N);
    hipMemsetAsync(stats, 0, 256 * 4, stream);
    agg_kernel<128, true, true, unsigned short><<<gA, 256, 0, stream>>>(
        hwB, rowptr, epack, dinv, sarr, cvec, b3, hA, stats, N);

    // layer 4 (COLS=64, f32 out, no stats)
    prep_kernel<true><<<8, 256, 0, stream>>>(W4, 64, stats, g3, be3, invN, Wt, cvec);
    gemm_mfma<64, false><<<gG, 256, 0, stream>>>(hA, Wt, hwB, N);
    agg_kernel<64, false, true, float><<<gA, 256, 0, stream>>>(
        hwB, rowptr, epack, dinv, sarr, cvec, b4, (float*)d_out, nullptr, N);
}